// Round 8
// baseline (236.319 us; speedup 1.0000x reference)
//
#include <hip/hip_runtime.h>
#include <hip/hip_bf16.h>

#define N_NODES 50000
#define N_EDGES 800000
#define C 96
#define C3 288
#define HID 32
#define GPB 8           // nodes (32-lane half-wave groups) per 256-thread block
#define NB_NODES 196    // ceil(50000/256)

// ---------------- counting sort by dst: hist -> scan -> fill ----------------

__global__ void k_zero(int* __restrict__ count) {
    int i = blockIdx.x * 256 + threadIdx.x;
    if (i < N_NODES) count[i] = 0;
}

// 4 edges per thread, int4 read, independent atomics
__global__ void k_hist(const int* __restrict__ dst, int* __restrict__ count) {
    int e4 = blockIdx.x * 256 + threadIdx.x;
    if (e4 < N_EDGES / 4) {
        int4 d = ((const int4*)dst)[e4];
        atomicAdd(&count[d.x], 1);
        atomicAdd(&count[d.y], 1);
        atomicAdd(&count[d.z], 1);
        atomicAdd(&count[d.w], 1);
    }
}

__global__ void k_scan1(const int* __restrict__ count, int* __restrict__ rowstart,
                        int* __restrict__ blocksum) {
    __shared__ int s[256];
    int t = threadIdx.x;
    int i = blockIdx.x * 256 + t;
    int v = (i < N_NODES) ? count[i] : 0;
    s[t] = v;
    __syncthreads();
    for (int off = 1; off < 256; off <<= 1) {
        int add = (t >= off) ? s[t - off] : 0;
        __syncthreads();
        s[t] += add;
        __syncthreads();
    }
    if (i < N_NODES) rowstart[i] = s[t] - v;     // exclusive within block
    if (t == 255) blocksum[blockIdx.x] = s[255];
}

// merged scan2+scan3: every block redundantly scans the 196 block sums (cheap),
// then applies its own prefix and initializes cursor.
__global__ void k_scan23(int* __restrict__ rowstart, const int* __restrict__ blocksum,
                         int* __restrict__ cursor) {
    __shared__ int s[256];
    int t = threadIdx.x;
    s[t] = (t < NB_NODES) ? blocksum[t] : 0;
    __syncthreads();
    for (int off = 1; off < 256; off <<= 1) {
        int add = (t >= off) ? s[t - off] : 0;
        __syncthreads();
        s[t] += add;
        __syncthreads();
    }
    // exclusive prefix for this block
    __shared__ int pre;
    if (t == 0) pre = (blockIdx.x == 0) ? 0 : s[blockIdx.x - 1];
    __syncthreads();
    int i = blockIdx.x * 256 + t;
    if (i < N_NODES) {
        int rs = rowstart[i] + pre;
        rowstart[i] = rs;
        cursor[i] = rs;
    }
    if (i == 0) rowstart[N_NODES] = N_EDGES;
}

// 4 edges per thread; 4 independent atomic+store chains in flight
__global__ void k_fill(const int* __restrict__ src, const int* __restrict__ dst,
                       int* __restrict__ cursor, int* __restrict__ srcs) {
    int e4 = blockIdx.x * 256 + threadIdx.x;
    if (e4 < N_EDGES / 4) {
        int4 sv = ((const int4*)src)[e4];
        int4 dv = ((const int4*)dst)[e4];
        int p0 = atomicAdd(&cursor[dv.x], 1);
        int p1 = atomicAdd(&cursor[dv.y], 1);
        int p2 = atomicAdd(&cursor[dv.z], 1);
        int p3 = atomicAdd(&cursor[dv.w], 1);
        srcs[p0] = sv.x;
        srcs[p1] = sv.y;
        srcs[p2] = sv.z;
        srcs[p3] = sv.w;
    }
}

// ---------------- Wf = Wg @ W1  (96 x 32) ----------------

__global__ void k_wf(const float* __restrict__ Wg, const float* __restrict__ W1,
                     float* __restrict__ Wf) {
    int kt = blockIdx.x * 256 + threadIdx.x;
    if (kt >= C * HID) return;
    int k = kt >> 5, j = kt & 31;
    float acc = 0.f;
    for (int m = 0; m < C3; ++m)
        acc += Wg[k * C3 + m] * W1[m * HID + j];
    Wf[k * HID + j] = acc;
}

// ---------------- z[i] = bf16( (dinv_i * x[i]) @ Wf )   (N x 32, 3.2 MB) ----

__global__ __launch_bounds__(256) void k_z(
        const float* __restrict__ x, const int* __restrict__ count,
        const float* __restrict__ Wf, __hip_bfloat16* __restrict__ z) {
    __shared__ float xs[GPB][C];         // 3 KB; each half-wave owns its slice
    const int t = threadIdx.x, l = t & 31, grp = t >> 5;
    const int g = blockIdx.x * GPB + grp;          // exact grid: 6250*8 = 50000
    const float di = rsqrtf((float)(count[g] + 1));
    const float* xr = x + (size_t)g * C;
    // stage own row scaled by dinv; same half-wave reads it back (in-wave LDS order)
    xs[grp][l]      = xr[l]      * di;
    xs[grp][l + 32] = xr[l + 32] * di;
    xs[grp][l + 64] = xr[l + 64] * di;
    float acc = 0.f;
    #pragma unroll 8
    for (int k = 0; k < C; ++k)
        acc = fmaf(xs[grp][k], Wf[k * HID + l], acc);   // Wf: 12 KB, L1-resident
    z[(size_t)g * HID + l] = __float2bfloat16(acc);
}

// ---------------- fused gather(z bf16) + relu + W2 + residual; barrier-free ----

__global__ __launch_bounds__(256) void k_fused(
        const int* __restrict__ rowstart, const int* __restrict__ srcs,
        const __hip_bfloat16* __restrict__ z, const float* __restrict__ x,
        const float* __restrict__ b1, const float* __restrict__ W2,
        const float* __restrict__ b2, float* __restrict__ out) {
    const int t = threadIdx.x, l = t & 31;
    const int g = blockIdx.x * GPB + (t >> 5);     // exact grid
    const int rs = rowstart[g], re = rowstart[g + 1];
    const float di = rsqrtf((float)(re - rs + 1));

    // gather in 32-dim bf16 z-space: one 64 B line per edge
    float h = __bfloat162float(z[(size_t)g * HID + l]);   // self-loop term
    int e = rs;
    for (; e + 8 <= re; e += 8) {
        int s0 = srcs[e],     s1 = srcs[e + 1], s2 = srcs[e + 2], s3 = srcs[e + 3];
        int s4 = srcs[e + 4], s5 = srcs[e + 5], s6 = srcs[e + 6], s7 = srcs[e + 7];
        float v0 = __bfloat162float(z[(size_t)s0 * HID + l]);
        float v1 = __bfloat162float(z[(size_t)s1 * HID + l]);
        float v2 = __bfloat162float(z[(size_t)s2 * HID + l]);
        float v3 = __bfloat162float(z[(size_t)s3 * HID + l]);
        float v4 = __bfloat162float(z[(size_t)s4 * HID + l]);
        float v5 = __bfloat162float(z[(size_t)s5 * HID + l]);
        float v6 = __bfloat162float(z[(size_t)s6 * HID + l]);
        float v7 = __bfloat162float(z[(size_t)s7 * HID + l]);
        h += ((v0 + v1) + (v2 + v3)) + ((v4 + v5) + (v6 + v7));
    }
    for (; e + 2 <= re; e += 2) {
        int s0 = srcs[e], s1 = srcs[e + 1];
        h += __bfloat162float(z[(size_t)s0 * HID + l])
           + __bfloat162float(z[(size_t)s1 * HID + l]);
    }
    if (e < re) h += __bfloat162float(z[(size_t)srcs[e] * HID + l]);

    const float hid = fmaxf(fmaf(h, di, b1[l]), 0.f);

    // out channels l, l+32, l+64; hid broadcast via in-wave shuffle
    float o0 = b2[l], o1 = b2[l + 32], o2 = b2[l + 64];
    const int base = t & 32;                       // half-wave base lane within wave
    #pragma unroll
    for (int hh = 0; hh < HID; ++hh) {
        float hv = __shfl(hid, base + hh, 64);
        o0 = fmaf(hv, W2[hh * C + l],      o0);    // W2: 12 KB, L1-resident
        o1 = fmaf(hv, W2[hh * C + l + 32], o1);
        o2 = fmaf(hv, W2[hh * C + l + 64], o2);
    }
    const float* xr = x + (size_t)g * C;
    float* orow = out + (size_t)g * C;
    orow[l]      = xr[l]      + o0;
    orow[l + 32] = xr[l + 32] + o1;
    orow[l + 64] = xr[l + 64] + o2;
}

// ---------------- launch ----------------

extern "C" void kernel_launch(void* const* d_in, const int* in_sizes, int n_in,
                              void* d_out, int out_size, void* d_ws, size_t ws_size,
                              hipStream_t stream) {
    const float* x   = (const float*)d_in[0];
    const float* Wg  = (const float*)d_in[1];
    const float* W1  = (const float*)d_in[2];
    const float* b1  = (const float*)d_in[3];
    const float* W2  = (const float*)d_in[4];
    const float* b2  = (const float*)d_in[5];
    const int* ei  = (const int*)d_in[6];
    const int* src = ei;                 // edge_index[0]
    const int* dst = ei + N_EDGES;       // edge_index[1]
    float* out = (float*)d_out;

    // workspace layout (~7 MB)
    char* w = (char*)d_ws;
    int*   count    = (int*)w;                 w += N_NODES * 4;
    int*   rowstart = (int*)w;                 w += (N_NODES + 1) * 4;
    int*   cursor   = (int*)w;                 w += N_NODES * 4;
    int*   blocksum = (int*)w;                 w += 256 * 4;
    int*   srcs     = (int*)w;                 w += N_EDGES * 4;
    float* Wf       = (float*)w;               w += C * HID * 4;
    __hip_bfloat16* z = (__hip_bfloat16*)w;    /* N*HID bf16, 3.2 MB */

    const int nb_e4 = (N_EDGES / 4 + 255) / 256;   // 782

    k_zero  <<<NB_NODES, 256, 0, stream>>>(count);
    k_hist  <<<nb_e4,    256, 0, stream>>>(dst, count);
    k_wf    <<<(C * HID + 255) / 256, 256, 0, stream>>>(Wg, W1, Wf);
    k_scan1 <<<NB_NODES, 256, 0, stream>>>(count, rowstart, blocksum);
    k_scan23<<<NB_NODES, 256, 0, stream>>>(rowstart, blocksum, cursor);
    k_z     <<<N_NODES / GPB, 256, 0, stream>>>(x, count, Wf, z);
    k_fill  <<<nb_e4,    256, 0, stream>>>(src, dst, cursor, srcs);
    k_fused <<<N_NODES / GPB, 256, 0, stream>>>(rowstart, srcs, z, x, b1, W2, b2, out);
}

// Round 10
// 177.493 us; speedup vs baseline: 1.3314x; 1.3314x over previous
//
#include <hip/hip_runtime.h>
#include <hip/hip_bf16.h>

#define N_NODES 50000
#define N_EDGES 800000
#define C 96
#define C3 288
#define HID 32
#define GPB 8            // nodes (32-lane half-wave groups) per 256-thread block
#define BSH 7            // bucket = dst >> 7  (128 nodes per bucket)
#define NBUCK 391        // ceil(50000 / 128)
#define E4 (N_EDGES / 4) // 200000
#define CBLK 391         // ceil(E4 / 512): edge blocks for kA/kC (2048 edges each)

// ---------------- Wf = Wg @ W1  (96 x 32); also zeros bucket hist ----------------

__global__ void k_wf(const float* __restrict__ Wg, const float* __restrict__ W1,
                     float* __restrict__ Wf, int* __restrict__ gbhist) {
    int kt = blockIdx.x * 256 + threadIdx.x;
    if (kt < NBUCK) gbhist[kt] = 0;
    if (kt >= C * HID) return;
    int k = kt >> 5, j = kt & 31;
    float acc = 0.f;
    for (int m = 0; m < C3; ++m)
        acc += Wg[k * C3 + m] * W1[m * HID + j];
    Wf[k * HID + j] = acc;
}

// ---------------- kA: bucket histogram (LDS-reduced) ----------------

__global__ __launch_bounds__(512) void kA(const int* __restrict__ dst,
                                          int* __restrict__ gbhist) {
    __shared__ int h[NBUCK];
    const int t = threadIdx.x;
    for (int i = t; i < NBUCK; i += 512) h[i] = 0;
    __syncthreads();
    int e4 = blockIdx.x * 512 + t;
    if (e4 < E4) {
        int4 d = ((const int4*)dst)[e4];
        atomicAdd(&h[d.x >> BSH], 1);
        atomicAdd(&h[d.y >> BSH], 1);
        atomicAdd(&h[d.z >> BSH], 1);
        atomicAdd(&h[d.w >> BSH], 1);
    }
    __syncthreads();
    for (int i = t; i < NBUCK; i += 512)
        if (h[i]) atomicAdd(&gbhist[i], h[i]);
}

// ---------------- kB: scan bucket counts -> bases + cursors ----------------

__global__ __launch_bounds__(512) void kB(const int* __restrict__ gbhist,
                                          int* __restrict__ bucket_base,
                                          int* __restrict__ bucket_cursor,
                                          int* __restrict__ rowstart) {
    __shared__ int s[512];
    const int t = threadIdx.x;
    int v = (t < NBUCK) ? gbhist[t] : 0;
    s[t] = v;
    __syncthreads();
    for (int off = 1; off < 512; off <<= 1) {
        int a = (t >= off) ? s[t - off] : 0;
        __syncthreads();
        s[t] += a;
        __syncthreads();
    }
    if (t < NBUCK) { int ex = s[t] - v; bucket_base[t] = ex; bucket_cursor[t] = ex; }
    if (t == 0) { bucket_base[NBUCK] = N_EDGES; rowstart[N_NODES] = N_EDGES; }
}

// ---------------- kC: partition edges into bucket runs (coalesced writes) ----

__global__ __launch_bounds__(512) void kC(const int* __restrict__ src,
                                          const int* __restrict__ dst,
                                          int* __restrict__ bucket_cursor,
                                          unsigned int* __restrict__ packed) {
    __shared__ int h[NBUCK];            // block-local bucket counts
    __shared__ int pre[NBUCK];          // exclusive prefix of h
    __shared__ int runbase[NBUCK];      // global reservation per bucket
    __shared__ int lcur[NBUCK];         // staging cursor
    __shared__ int s[512];              // scan scratch
    __shared__ unsigned int staged[2048];
    __shared__ unsigned short sb[2048]; // bucket id of staged slot
    const int t = threadIdx.x;
    for (int i = t; i < NBUCK; i += 512) h[i] = 0;
    __syncthreads();

    const int e4 = blockIdx.x * 512 + t;
    const bool valid = e4 < E4;
    int4 sv, dv;
    if (valid) {
        sv = ((const int4*)src)[e4];
        dv = ((const int4*)dst)[e4];
        atomicAdd(&h[dv.x >> BSH], 1);
        atomicAdd(&h[dv.y >> BSH], 1);
        atomicAdd(&h[dv.z >> BSH], 1);
        atomicAdd(&h[dv.w >> BSH], 1);
    }
    __syncthreads();

    // exclusive prefix of h over NBUCK
    int v = (t < NBUCK) ? h[t] : 0;
    s[t] = v;
    __syncthreads();
    for (int off = 1; off < 512; off <<= 1) {
        int a = (t >= off) ? s[t - off] : 0;
        __syncthreads();
        s[t] += a;
        __syncthreads();
    }
    if (t < NBUCK) {
        int ex = s[t] - v;
        pre[t] = ex;
        lcur[t] = ex;
        if (v) runbase[t] = atomicAdd(&bucket_cursor[t], v);
    }
    __syncthreads();

    // stage edges grouped by bucket; pack src (16b) | dst_local (7b @ bit16)
    if (valid) {
        int b0 = dv.x >> BSH, p0 = atomicAdd(&lcur[b0], 1);
        staged[p0] = (unsigned)sv.x | ((unsigned)(dv.x & 127) << 16); sb[p0] = (unsigned short)b0;
        int b1 = dv.y >> BSH, p1 = atomicAdd(&lcur[b1], 1);
        staged[p1] = (unsigned)sv.y | ((unsigned)(dv.y & 127) << 16); sb[p1] = (unsigned short)b1;
        int b2 = dv.z >> BSH, p2 = atomicAdd(&lcur[b2], 1);
        staged[p2] = (unsigned)sv.z | ((unsigned)(dv.z & 127) << 16); sb[p2] = (unsigned short)b2;
        int b3 = dv.w >> BSH, p3 = atomicAdd(&lcur[b3], 1);
        staged[p3] = (unsigned)sv.w | ((unsigned)(dv.w & 127) << 16); sb[p3] = (unsigned short)b3;
    }
    __syncthreads();

    // write runs out: consecutive staged slots -> consecutive global slots per run
    int cntT = N_EDGES - blockIdx.x * 2048;
    if (cntT > 2048) cntT = 2048;
    for (int i = t; i < cntT; i += 512) {
        int b = sb[i];
        packed[runbase[b] + (i - pre[b])] = staged[i];
    }
}

// ---------------- kD: per-bucket finalize -> rowstart + srcs (coalesced) ----

__global__ __launch_bounds__(256) void kD(const int* __restrict__ bucket_base,
                                          const unsigned int* __restrict__ packed,
                                          int* __restrict__ rowstart,
                                          int* __restrict__ srcs) {
    __shared__ int cnt[128], pre2[128], cur[128];
    const int b = blockIdx.x, t = threadIdx.x;
    const int base = bucket_base[b];
    const int cnt_e = bucket_base[b + 1] - base;
    if (t < 128) cnt[t] = 0;
    __syncthreads();
    for (int i = t; i < cnt_e; i += 256)
        atomicAdd(&cnt[(packed[base + i] >> 16) & 127], 1);
    __syncthreads();
    int v = (t < 128) ? cnt[t] : 0;
    if (t < 128) pre2[t] = v;
    __syncthreads();
    for (int off = 1; off < 128; off <<= 1) {
        int a = (t < 128 && t >= off) ? pre2[t - off] : 0;
        __syncthreads();
        if (t < 128) pre2[t] += a;
        __syncthreads();
    }
    const int node = b * 128 + t;
    if (t < 128) {
        int ex = pre2[t] - v;            // exclusive prefix
        cur[t] = ex;
        if (node < N_NODES) rowstart[node] = base + ex;
    }
    __syncthreads();
    for (int i = t; i < cnt_e; i += 256) {
        unsigned p = packed[base + i];
        int pos = atomicAdd(&cur[(p >> 16) & 127], 1);
        srcs[base + pos] = (int)(p & 0xFFFFu);
    }
}

// ---------------- z[i] = bf16( (dinv_i * x[i]) @ Wf )   (N x 32, 3.2 MB) ----

__global__ __launch_bounds__(256) void k_z(
        const float* __restrict__ x, const int* __restrict__ rowstart,
        const float* __restrict__ Wf, __hip_bfloat16* __restrict__ z) {
    __shared__ float xs[GPB][C];
    const int t = threadIdx.x, l = t & 31, grp = t >> 5;
    const int g = blockIdx.x * GPB + grp;          // exact grid: 6250*8 = 50000
    const float di = rsqrtf((float)(rowstart[g + 1] - rowstart[g] + 1));
    const float* xr = x + (size_t)g * C;
    xs[grp][l]      = xr[l]      * di;
    xs[grp][l + 32] = xr[l + 32] * di;
    xs[grp][l + 64] = xr[l + 64] * di;
    float acc = 0.f;
    #pragma unroll 8
    for (int k = 0; k < C; ++k)
        acc = fmaf(xs[grp][k], Wf[k * HID + l], acc);
    z[(size_t)g * HID + l] = __float2bfloat16(acc);
}

// ---------------- fused gather(z bf16) + relu + W2 + residual ----------------

__global__ __launch_bounds__(256) void k_fused(
        const int* __restrict__ rowstart, const int* __restrict__ srcs,
        const __hip_bfloat16* __restrict__ z, const float* __restrict__ x,
        const float* __restrict__ b1, const float* __restrict__ W2,
        const float* __restrict__ b2, float* __restrict__ out) {
    const int t = threadIdx.x, l = t & 31;
    const int g = blockIdx.x * GPB + (t >> 5);
    const int rs = rowstart[g], re = rowstart[g + 1];
    const float di = rsqrtf((float)(re - rs + 1));

    float h = __bfloat162float(z[(size_t)g * HID + l]);   // self-loop term
    int e = rs;
    for (; e + 8 <= re; e += 8) {
        int s0 = srcs[e],     s1 = srcs[e + 1], s2 = srcs[e + 2], s3 = srcs[e + 3];
        int s4 = srcs[e + 4], s5 = srcs[e + 5], s6 = srcs[e + 6], s7 = srcs[e + 7];
        float v0 = __bfloat162float(z[(size_t)s0 * HID + l]);
        float v1 = __bfloat162float(z[(size_t)s1 * HID + l]);
        float v2 = __bfloat162float(z[(size_t)s2 * HID + l]);
        float v3 = __bfloat162float(z[(size_t)s3 * HID + l]);
        float v4 = __bfloat162float(z[(size_t)s4 * HID + l]);
        float v5 = __bfloat162float(z[(size_t)s5 * HID + l]);
        float v6 = __bfloat162float(z[(size_t)s6 * HID + l]);
        float v7 = __bfloat162float(z[(size_t)s7 * HID + l]);
        h += ((v0 + v1) + (v2 + v3)) + ((v4 + v5) + (v6 + v7));
    }
    for (; e + 2 <= re; e += 2) {
        int s0 = srcs[e], s1 = srcs[e + 1];
        h += __bfloat162float(z[(size_t)s0 * HID + l])
           + __bfloat162float(z[(size_t)s1 * HID + l]);
    }
    if (e < re) h += __bfloat162float(z[(size_t)srcs[e] * HID + l]);

    const float hid = fmaxf(fmaf(h, di, b1[l]), 0.f);

    float o0 = b2[l], o1 = b2[l + 32], o2 = b2[l + 64];
    const int base = t & 32;
    #pragma unroll
    for (int hh = 0; hh < HID; ++hh) {
        float hv = __shfl(hid, base + hh, 64);
        o0 = fmaf(hv, W2[hh * C + l],      o0);
        o1 = fmaf(hv, W2[hh * C + l + 32], o1);
        o2 = fmaf(hv, W2[hh * C + l + 64], o2);
    }
    const float* xr = x + (size_t)g * C;
    float* orow = out + (size_t)g * C;
    orow[l]      = xr[l]      + o0;
    orow[l + 32] = xr[l + 32] + o1;
    orow[l + 64] = xr[l + 64] + o2;
}

// ---------------- launch ----------------

extern "C" void kernel_launch(void* const* d_in, const int* in_sizes, int n_in,
                              void* d_out, int out_size, void* d_ws, size_t ws_size,
                              hipStream_t stream) {
    const float* x   = (const float*)d_in[0];
    const float* Wg  = (const float*)d_in[1];
    const float* W1  = (const float*)d_in[2];
    const float* b1  = (const float*)d_in[3];
    const float* W2  = (const float*)d_in[4];
    const float* b2  = (const float*)d_in[5];
    const int* ei  = (const int*)d_in[6];
    const int* src = ei;                 // edge_index[0]
    const int* dst = ei + N_EDGES;       // edge_index[1]
    float* out = (float*)d_out;

    // workspace layout (~10 MB)
    char* w = (char*)d_ws;
    int* gbhist        = (int*)w;             w += NBUCK * 4;
    int* bucket_base   = (int*)w;             w += (NBUCK + 1) * 4;
    int* bucket_cursor = (int*)w;             w += NBUCK * 4;
    int* rowstart      = (int*)w;             w += (N_NODES + 1) * 4;
    unsigned int* packed = (unsigned int*)w;  w += N_EDGES * 4;
    int* srcs          = (int*)w;             w += N_EDGES * 4;
    float* Wf          = (float*)w;           w += C * HID * 4;
    __hip_bfloat16* z  = (__hip_bfloat16*)w;  /* N*HID bf16, 3.2 MB */

    k_wf   <<<(C * HID + 255) / 256, 256, 0, stream>>>(Wg, W1, Wf, gbhist);
    kA     <<<CBLK, 512, 0, stream>>>(dst, gbhist);
    kB     <<<1,    512, 0, stream>>>(gbhist, bucket_base, bucket_cursor, rowstart);
    kC     <<<CBLK, 512, 0, stream>>>(src, dst, bucket_cursor, packed);
    kD     <<<NBUCK, 256, 0, stream>>>(bucket_base, packed, rowstart, srcs);
    k_z    <<<N_NODES / GPB, 256, 0, stream>>>(x, rowstart, Wf, z);
    k_fused<<<N_NODES / GPB, 256, 0, stream>>>(rowstart, srcs, z, x, b1, W2, b2, out);
}